// Round 10
// baseline (173.045 us; speedup 1.0000x reference)
//
#include <hip/hip_runtime.h>
#include <hip/hip_bf16.h>

#define NN 100000
#define NE 600000
#define DD 128
#define SLOPE 0.22916666666666666f
#define NB1 98  // ceil(NN/1024)
#define SENT ((500u << 17) | 100000u)  // decodes to zero rows hb[NN], relb[500]
#define NBKT 196                      // ceil(NN/512)
#define EPB 2048                      // edges per bin_scatter block
#define NBINB 293                     // ceil(NE/EPB)
#define CAP 12288                     // staging capacity per bucket
#define NROWB 1563                    // ceil(NN/64) row-blocks for fused layer

typedef __attribute__((ext_vector_type(4))) float f32x4;
typedef __attribute__((ext_vector_type(4))) unsigned u32x4;
typedef __attribute__((ext_vector_type(8))) short s16x8;
typedef __attribute__((ext_vector_type(4))) short s16x4;

__device__ __forceinline__ unsigned short f2b(float f) {
  union { float f; unsigned u; } v; v.f = f;
  unsigned u = v.u;
  return (unsigned short)((u + 0x7fffu + ((u >> 16) & 1u)) >> 16);
}
__device__ __forceinline__ float b2f(short s) {
  union { unsigned u; float f; } v;
  v.u = ((unsigned)(unsigned short)s) << 16;
  return v.f;
}
// padded degree: 4*ceil(deg/4); deg from norm (deg0 nodes -> 4 sentinel slots)
__device__ __forceinline__ int pdegf(float nm) {
  int d = (int)(1.0f / nm + 0.5f);
  return (d + 3) & ~3;
}

// K1: ent->bf16 (+zero row NN in entb AND h1b), rel->bf16 (+zero row 500),
// Wt in MFMA-fragment order; blocks<NB1 also run scan_a; block NB1 zeroes bktcur.
__global__ void prep_plus(const float* __restrict__ ent, const float* __restrict__ rel,
                          const float* __restrict__ Wr0, const float* __restrict__ Wl0,
                          const float* __restrict__ Wr1, const float* __restrict__ Wl1,
                          const float* __restrict__ norm,
                          unsigned short* __restrict__ entb, unsigned short* __restrict__ relb,
                          unsigned short* __restrict__ Wt, unsigned short* __restrict__ h1b,
                          int* __restrict__ psum, int* __restrict__ bktcur) {
  __shared__ int lds[256];
  int i = blockIdx.x * blockDim.x + threadIdx.x;
  if (i < (NN + 1) * 16) {
    s16x8 o = {0, 0, 0, 0, 0, 0, 0, 0};
    if (i < NN * 16) {
      f32x4 v0 = *(const f32x4*)(ent + (size_t)i * 8);
      f32x4 v1 = *(const f32x4*)(ent + (size_t)i * 8 + 4);
      o[0] = (short)f2b(v0[0]); o[1] = (short)f2b(v0[1]);
      o[2] = (short)f2b(v0[2]); o[3] = (short)f2b(v0[3]);
      o[4] = (short)f2b(v1[0]); o[5] = (short)f2b(v1[1]);
      o[6] = (short)f2b(v1[2]); o[7] = (short)f2b(v1[3]);
    }
    *(s16x8*)(entb + (size_t)i * 8) = o;
    if (i >= NN * 16) *(s16x8*)(h1b + (size_t)i * 8) = o;  // zero sentinel row of h1 table
  }
  if (i < 501 * 16) {
    s16x8 o = {0, 0, 0, 0, 0, 0, 0, 0};
    if (i < 500 * 16) {
      f32x4 v0 = *(const f32x4*)(rel + (size_t)i * 8);
      f32x4 v1 = *(const f32x4*)(rel + (size_t)i * 8 + 4);
      o[0] = (short)f2b(v0[0]); o[1] = (short)f2b(v0[1]);
      o[2] = (short)f2b(v0[2]); o[3] = (short)f2b(v0[3]);
      o[4] = (short)f2b(v1[0]); o[5] = (short)f2b(v1[1]);
      o[6] = (short)f2b(v1[2]); o[7] = (short)f2b(v1[3]);
    }
    *(s16x8*)(relb + (size_t)i * 8) = o;
  }
  if (i < 8192) {  // 2 layers x 4096 fragment units x 8 shorts
    int L = i >> 12, rem = i & 4095;
    int n = rem >> 9, k = (rem >> 6) & 7, lane = rem & 63;
    int c = n * 16 + (lane & 15);
    int kk0 = k * 32 + (lane >> 4) * 8;
    const float* Wr = L ? Wr1 : Wr0;
    const float* Wl = L ? Wl1 : Wl0;
    s16x8 o;
#pragma unroll
    for (int t = 0; t < 8; t++) {
      int kk = kk0 + t;
      float v = (kk < DD) ? Wr[kk * DD + c] : Wl[(kk - DD) * DD + c];
      o[t] = (short)f2b(v);
    }
    *(s16x8*)(Wt + (size_t)i * 8) = o;
  }
  // scan_a role
  if (blockIdx.x < NB1) {
    int b = blockIdx.x, t = threadIdx.x;
    int base = b * 1024 + t * 4;
    int s = 0;
#pragma unroll
    for (int j = 0; j < 4; j++) { int ii = base + j; if (ii < NN) s += pdegf(norm[ii]); }
    lds[t] = s; __syncthreads();
    for (int st = 128; st > 0; st >>= 1) { if (t < st) lds[t] += lds[t + st]; __syncthreads(); }
    if (t == 0) psum[b] = lds[0];
  } else if (blockIdx.x == NB1 && threadIdx.x < NBKT) {
    bktcur[threadIdx.x] = 0;
  }
}

// K2: exclusive scan of chunk sums; writes off[NN] = total padded slots
__global__ void scan_b(int* __restrict__ psum, int* __restrict__ off) {
  __shared__ int lds[128];
  int t = threadIdx.x;
  lds[t] = (t < NB1) ? psum[t] : 0; __syncthreads();
  for (int st = 1; st < 128; st <<= 1) {
    int v = (t >= st) ? lds[t - st] : 0;
    __syncthreads();
    lds[t] += v;
    __syncthreads();
  }
  if (t == 127) off[NN] = lds[127];
  if (t < NB1) psum[t] = t ? lds[t - 1] : 0;
}

// K3: blocks<NB1 run scan_c (node offsets); remaining blocks run bin_scatter.
__global__ void scanc_bin(const float* __restrict__ norm, const int* __restrict__ psum,
                          int* __restrict__ off,
                          const int* __restrict__ src, const int* __restrict__ dst,
                          const int* __restrict__ rid, int* __restrict__ bktcur,
                          unsigned* __restrict__ sval, unsigned short* __restrict__ sdst) {
  __shared__ int lds[256];
  __shared__ int hist[NBKT];
  __shared__ int base[NBKT];
  __shared__ int rnk[NBKT];
  int tid = threadIdx.x;
  if (blockIdx.x < NB1) {
    int b = blockIdx.x;
    int bb = b * 1024 + tid * 4;
    int v[4]; int s = 0;
#pragma unroll
    for (int j = 0; j < 4; j++) { int i = bb + j; v[j] = (i < NN) ? pdegf(norm[i]) : 0; s += v[j]; }
    lds[tid] = s; __syncthreads();
    for (int st = 1; st < 256; st <<= 1) {
      int u = (tid >= st) ? lds[tid - st] : 0;
      __syncthreads();
      lds[tid] += u;
      __syncthreads();
    }
    int run = (tid ? lds[tid - 1] : 0) + psum[b];
#pragma unroll
    for (int j = 0; j < 4; j++) {
      int i = bb + j;
      if (i < NN) { off[i] = run; run += v[j]; }
    }
  } else {
    int b = blockIdx.x - NB1;
    int e0 = b * EPB;
    for (int t = tid; t < NBKT; t += 256) hist[t] = 0;
    __syncthreads();
    int d[8];
#pragma unroll
    for (int j = 0; j < 8; j++) {
      int e = e0 + tid + j * 256;
      d[j] = (e < NE) ? dst[e] : -1;
      if (d[j] >= 0) atomicAdd(&hist[d[j] >> 9], 1);
    }
    __syncthreads();
    for (int t = tid; t < NBKT; t += 256) {
      base[t] = hist[t] ? atomicAdd(&bktcur[t], hist[t]) : 0;
      rnk[t] = 0;
    }
    __syncthreads();
#pragma unroll
    for (int j = 0; j < 8; j++) {
      if (d[j] >= 0) {
        int e = e0 + tid + j * 256;
        int bk = d[j] >> 9;
        int r = atomicAdd(&rnk[bk], 1);
        int pos = base[bk] + r;
        if (pos < CAP) {
          sval[(size_t)bk * CAP + pos] = (unsigned)src[e] | ((unsigned)rid[e] << 17);
          sdst[(size_t)bk * CAP + pos] = (unsigned short)(d[j] & 511);
        }
      }
    }
  }
}

// K4: one block per bucket; place staged edges at final epack slots, sentinel-pad.
__global__ void bin_sort(const int* __restrict__ bktcur, const unsigned* __restrict__ sval,
                         const unsigned short* __restrict__ sdst, const int* __restrict__ off,
                         unsigned* __restrict__ epack) {
  __shared__ int cur[512];
  int b = blockIdx.x, tid = threadIdx.x;
  int g0 = b << 9;
  for (int t = tid; t < 512; t += 256) {
    int g = g0 + t;
    cur[t] = (g < NN) ? off[g] : 0;
  }
  __syncthreads();
  int scnt = min(bktcur[b], CAP);
  for (int i = tid; i < scnt; i += 256) {
    unsigned v = sval[(size_t)b * CAP + i];
    int gl = sdst[(size_t)b * CAP + i];
    int pos = atomicAdd(&cur[gl], 1);
    epack[pos] = v;
  }
  __syncthreads();
  for (int t = tid; t < 512; t += 256) {
    int g = g0 + t;
    if (g < NN) {
      int s = cur[t], e = off[g + 1];
      for (; s < e; s++) epack[s] = SENT;
    }
  }
}

// K5/K6: fused gather + MFMA layer. Per block: 64 rows.
// Gather: 16 groups x 32 lanes, 4 nodes each; accumulate fp32 over CSR slots;
// fold norm; write bf16 row into LDS in A-FRAGMENT layout
// (writer-lane c holds cols 4c..4c+3 -> ks=c>>3, lane64=((c>>1)&3)*16+row, t=(c&1)*4).
// MM: 8 waves = 4 row-tiles x 2 col-halves; A-pre from LDS (lane-linear reads),
// A-h direct from global, B (fragment-major) from LDS. LAYER 0 writes bf16 h1b
// (+relagg side product); LAYER 1 reads relagg, writes fp32 out.
template <int LAYER>
__launch_bounds__(512, 4)
__global__ void fused_layer(const unsigned short* __restrict__ hb,
                            const unsigned short* __restrict__ relb,
                            const unsigned short* __restrict__ relagg_r,
                            unsigned short* __restrict__ relagg_w,
                            const float* __restrict__ norm,
                            const int* __restrict__ off,
                            const unsigned* __restrict__ epack,
                            const unsigned short* __restrict__ Wt,
                            void* __restrict__ outp) {
  __shared__ unsigned short Alds[8192];   // 16 KB: [tile4][ks4][lane64][8]
  __shared__ unsigned short Blds[32768];  // 64 KB fragment-major weights
  int tid = threadIdx.x;

  // stage B (loads fly while gather runs after)
  for (int i = tid; i < 4096; i += 512)
    *(s16x8*)(&Blds[(size_t)i * 8]) = *(const s16x8*)(Wt + (size_t)i * 8);

  // ---- gather phase ----
  int gq = tid >> 5, c = tid & 31, cb = c << 2;
  int sidx = (c >> 3) * 512 + (((c >> 1) & 3) * 16 + gq) * 8 + (c & 1) * 4;
#pragma unroll
  for (int nn = 0; nn < 4; nn++) {
    int g = blockIdx.x * 64 + nn * 16 + gq;
    s16x4 p = {0, 0, 0, 0};
    if (g < NN) {
      int beg = off[g], end = off[g + 1];
      float h0 = 0.f, h1 = 0.f, h2 = 0.f, h3 = 0.f;
      float r0 = 0.f, r1 = 0.f, r2 = 0.f, r3 = 0.f;
      for (int e = beg; e < end; e += 4) {
        u32x4 w = *(const u32x4*)(epack + e);
        s16x4 hv[4], rv[4];
#pragma unroll
        for (int j = 0; j < 4; j++) {
          int s = (int)(w[j] & 0x1FFFFu);
          hv[j] = *(const s16x4*)(hb + (size_t)s * DD + cb);
          if (LAYER == 0) {
            int r = (int)(w[j] >> 17);
            rv[j] = *(const s16x4*)(relb + (size_t)r * DD + cb);
          }
        }
#pragma unroll
        for (int j = 0; j < 4; j++) {
          h0 += b2f(hv[j][0]); h1 += b2f(hv[j][1]);
          h2 += b2f(hv[j][2]); h3 += b2f(hv[j][3]);
          if (LAYER == 0) {
            r0 += b2f(rv[j][0]); r1 += b2f(rv[j][1]);
            r2 += b2f(rv[j][2]); r3 += b2f(rv[j][3]);
          }
        }
      }
      float nm = norm[g];
      if (LAYER == 0) {
        s16x4 q;
        q[0] = (short)f2b(r0 * nm); q[1] = (short)f2b(r1 * nm);
        q[2] = (short)f2b(r2 * nm); q[3] = (short)f2b(r3 * nm);
        *(s16x4*)(relagg_w + (size_t)g * DD + cb) = q;
        p[0] = (short)f2b((h0 + r0) * nm); p[1] = (short)f2b((h1 + r1) * nm);
        p[2] = (short)f2b((h2 + r2) * nm); p[3] = (short)f2b((h3 + r3) * nm);
      } else {
        s16x4 ra = *(const s16x4*)(relagg_r + (size_t)g * DD + cb);
        p[0] = (short)f2b(__builtin_fmaf(h0, nm, b2f(ra[0])));
        p[1] = (short)f2b(__builtin_fmaf(h1, nm, b2f(ra[1])));
        p[2] = (short)f2b(__builtin_fmaf(h2, nm, b2f(ra[2])));
        p[3] = (short)f2b(__builtin_fmaf(h3, nm, b2f(ra[3])));
      }
    }
    *(s16x4*)(&Alds[nn * 2048 + sidx]) = p;
  }
  __syncthreads();

  // ---- mm phase ----
  int wv = tid >> 6, l = tid & 63, l16 = l & 15, lh = l >> 4;
  int tile = wv >> 1, ch = wv & 1;
  int rowb = blockIdx.x * 64 + tile * 16;
  s16x8 a[8];
#pragma unroll
  for (int k = 0; k < 4; k++) a[k] = *(const s16x8*)(&Alds[tile * 2048 + k * 512 + l * 8]);
  const unsigned short* Ah = hb + (size_t)(rowb + l16) * DD + lh * 8;
#pragma unroll
  for (int k = 0; k < 4; k++) a[4 + k] = *(const s16x8*)(Ah + k * 32);

  f32x4 acc[4];
#pragma unroll
  for (int n = 0; n < 4; n++) acc[n] = (f32x4){0.f, 0.f, 0.f, 0.f};
#pragma unroll
  for (int n = 0; n < 4; n++) {
    int nb = ch * 4 + n;
#pragma unroll
    for (int k = 0; k < 8; k++) {
      s16x8 b = *(const s16x8*)(&Blds[(size_t)(nb * 8 + k) * 512 + l * 8]);
      acc[n] = __builtin_amdgcn_mfma_f32_16x16x32_bf16(a[k], b, acc[n], 0, 0, 0);
    }
  }
#pragma unroll
  for (int n = 0; n < 4; n++) {
    int nb = ch * 4 + n;
#pragma unroll
    for (int j = 0; j < 4; j++) {
      int gr = rowb + lh * 4 + j;
      if (gr < NN) {
        float x = acc[n][j];
        x = x > 0.f ? x : x * SLOPE;
        if (LAYER == 1) ((float*)outp)[(size_t)gr * DD + nb * 16 + l16] = x;
        else ((unsigned short*)outp)[(size_t)gr * DD + nb * 16 + l16] = f2b(x);
      }
    }
  }
}

extern "C" void kernel_launch(void* const* d_in, const int* in_sizes, int n_in,
                              void* d_out, int out_size, void* d_ws, size_t ws_size,
                              hipStream_t stream) {
  const float* ent  = (const float*)d_in[0];
  const float* rel  = (const float*)d_in[1];
  const float* norm = (const float*)d_in[2];
  const float* Wr0  = (const float*)d_in[3];
  const float* Wl0  = (const float*)d_in[4];
  const float* Wr1  = (const float*)d_in[5];
  const float* Wl1  = (const float*)d_in[6];
  const int* src = (const int*)d_in[7];
  const int* dst = (const int*)d_in[8];
  const int* rid = (const int*)d_in[9];
  float* out = (float*)d_out;

  char* ws = (char*)d_ws;
  unsigned short* entb = (unsigned short*)ws;                   // (NN+1)*256 = 25,600,256 B
  unsigned short* h1b  = (unsigned short*)(ws + 25600256);      // 25,700,000 B (row NN = zero sentinel)
  unsigned short* relagg = (unsigned short*)(ws + 51300256);    // 25,600,000 B
  unsigned short* Wt   = (unsigned short*)(ws + 76900256);      //    131,072 B (fragment-major)
  unsigned short* relb = (unsigned short*)(ws + 77031328);      // 501*256 = 128,256 B
  int* off  = (int*)(ws + 77159584);                            //    400,016 B
  int* psum = (int*)(ws + 77559600);                            //        512 B
  int* bktcur = (int*)(ws + 77560112);                          //        800 B
  unsigned* epack = (unsigned*)(ws + 77560912);                 //  4,001,792 B
  // staging aliases h1b (dead until fused_layer<0> epilogue; doesn't touch row NN):
  unsigned* sval = (unsigned*)h1b;                              // 9,633,792 B
  unsigned short* sdst = (unsigned short*)(ws + 25600256 + 9633792); // 4,816,896 B

  // K1: conversions + Wt + scan_a + bktcur zero
  prep_plus<<<((NN + 1) * 16 + 255) / 256, 256, 0, stream>>>(
      ent, rel, Wr0, Wl0, Wr1, Wl1, norm, entb, relb, Wt, h1b, psum, bktcur);
  // K2: scan of chunk sums
  scan_b<<<1, 128, 0, stream>>>(psum, off);
  // K3: node offsets || binned scatter to staging
  scanc_bin<<<NB1 + NBINB, 256, 0, stream>>>(norm, psum, off, src, dst, rid, bktcur, sval, sdst);
  // K4: bucket-local placement + sentinel pad
  bin_sort<<<NBKT, 256, 0, stream>>>(bktcur, sval, sdst, off, epack);

  // K5: layer 1 (gather ent+rel -> MFMA -> bf16 h1b; relagg side product)
  fused_layer<0><<<NROWB, 512, 0, stream>>>(entb, relb, relagg, relagg, norm, off, epack, Wt, h1b);
  // K6: layer 2 (gather h1 + relagg -> MFMA -> fp32 out)
  fused_layer<1><<<NROWB, 512, 0, stream>>>(h1b, relb, relagg, relagg, norm, off, epack, Wt + 32768, out);
}

// Round 11
// 147.369 us; speedup vs baseline: 1.1742x; 1.1742x over previous
//
#include <hip/hip_runtime.h>
#include <hip/hip_bf16.h>

#define NN 100000
#define NE 600000
#define DD 128
#define SLOPE 0.22916666666666666f
#define NB1 98  // ceil(NN/1024)
#define SENT ((500u << 17) | 100000u)  // decodes to zero rows hb[NN], relb[500]
#define NBKT 196                      // ceil(NN/512)
#define EPB 2048                      // edges per bin_scatter block
#define NBINB 293                     // ceil(NE/EPB)
#define CAP 12288                     // staging capacity per bucket
#define NTILE 6250                    // NN/16

typedef __attribute__((ext_vector_type(4))) float f32x4;
typedef __attribute__((ext_vector_type(2))) float f32x2;
typedef __attribute__((ext_vector_type(4))) unsigned u32x4;
typedef __attribute__((ext_vector_type(8))) short s16x8;
typedef __attribute__((ext_vector_type(4))) short s16x4;

__device__ __forceinline__ unsigned short f2b(float f) {
  union { float f; unsigned u; } v; v.f = f;
  unsigned u = v.u;
  return (unsigned short)((u + 0x7fffu + ((u >> 16) & 1u)) >> 16);
}
__device__ __forceinline__ float b2f(short s) {
  union { unsigned u; float f; } v;
  v.u = ((unsigned)(unsigned short)s) << 16;
  return v.f;
}
// unpack u32 (2 bf16) -> f32x2 {lo, hi}
__device__ __forceinline__ f32x2 bf2f2(unsigned u) {
  union { unsigned u; float f; } lo, hi;
  lo.u = u << 16; hi.u = u & 0xFFFF0000u;
  f32x2 r; r[0] = lo.f; r[1] = hi.f; return r;
}
// padded degree: 4*ceil(deg/4); deg from norm (deg0 nodes -> 4 sentinel slots)
__device__ __forceinline__ int pdegf(float nm) {
  int d = (int)(1.0f / nm + 0.5f);
  return (d + 3) & ~3;
}

// K1: ent->bf16 (+zero row NN), rel->bf16 (+zero row 500), Wt in MFMA-fragment
// order; blocks<NB1 also run scan_a; block NB1 zeroes bktcur.
__global__ void prep_plus(const float* __restrict__ ent, const float* __restrict__ rel,
                          const float* __restrict__ Wr0, const float* __restrict__ Wl0,
                          const float* __restrict__ Wr1, const float* __restrict__ Wl1,
                          const float* __restrict__ norm,
                          unsigned short* __restrict__ entb, unsigned short* __restrict__ relb,
                          unsigned short* __restrict__ Wt,
                          int* __restrict__ psum, int* __restrict__ bktcur) {
  __shared__ int lds[256];
  int i = blockIdx.x * blockDim.x + threadIdx.x;
  if (i < (NN + 1) * 16) {
    s16x8 o = {0, 0, 0, 0, 0, 0, 0, 0};
    if (i < NN * 16) {
      f32x4 v0 = *(const f32x4*)(ent + (size_t)i * 8);
      f32x4 v1 = *(const f32x4*)(ent + (size_t)i * 8 + 4);
      o[0] = (short)f2b(v0[0]); o[1] = (short)f2b(v0[1]);
      o[2] = (short)f2b(v0[2]); o[3] = (short)f2b(v0[3]);
      o[4] = (short)f2b(v1[0]); o[5] = (short)f2b(v1[1]);
      o[6] = (short)f2b(v1[2]); o[7] = (short)f2b(v1[3]);
    }
    *(s16x8*)(entb + (size_t)i * 8) = o;
  }
  if (i < 501 * 16) {
    s16x8 o = {0, 0, 0, 0, 0, 0, 0, 0};
    if (i < 500 * 16) {
      f32x4 v0 = *(const f32x4*)(rel + (size_t)i * 8);
      f32x4 v1 = *(const f32x4*)(rel + (size_t)i * 8 + 4);
      o[0] = (short)f2b(v0[0]); o[1] = (short)f2b(v0[1]);
      o[2] = (short)f2b(v0[2]); o[3] = (short)f2b(v0[3]);
      o[4] = (short)f2b(v1[0]); o[5] = (short)f2b(v1[1]);
      o[6] = (short)f2b(v1[2]); o[7] = (short)f2b(v1[3]);
    }
    *(s16x8*)(relb + (size_t)i * 8) = o;
  }
  if (i < 8192) {  // 2 layers x 4096 fragment units x 8 shorts
    int L = i >> 12, rem = i & 4095;
    int n = rem >> 9, k = (rem >> 6) & 7, lane = rem & 63;
    int c = n * 16 + (lane & 15);
    int kk0 = k * 32 + (lane >> 4) * 8;
    const float* Wr = L ? Wr1 : Wr0;
    const float* Wl = L ? Wl1 : Wl0;
    s16x8 o;
#pragma unroll
    for (int t = 0; t < 8; t++) {
      int kk = kk0 + t;
      float v = (kk < DD) ? Wr[kk * DD + c] : Wl[(kk - DD) * DD + c];
      o[t] = (short)f2b(v);
    }
    *(s16x8*)(Wt + (size_t)i * 8) = o;
  }
  if (blockIdx.x < NB1) {
    int b = blockIdx.x, t = threadIdx.x;
    int base = b * 1024 + t * 4;
    int s = 0;
#pragma unroll
    for (int j = 0; j < 4; j++) { int ii = base + j; if (ii < NN) s += pdegf(norm[ii]); }
    lds[t] = s; __syncthreads();
    for (int st = 128; st > 0; st >>= 1) { if (t < st) lds[t] += lds[t + st]; __syncthreads(); }
    if (t == 0) psum[b] = lds[0];
  } else if (blockIdx.x == NB1 && threadIdx.x < NBKT) {
    bktcur[threadIdx.x] = 0;
  }
}

// K2: exclusive scan of chunk sums; writes off[NN]
__global__ void scan_b(int* __restrict__ psum, int* __restrict__ off) {
  __shared__ int lds[128];
  int t = threadIdx.x;
  lds[t] = (t < NB1) ? psum[t] : 0; __syncthreads();
  for (int st = 1; st < 128; st <<= 1) {
    int v = (t >= st) ? lds[t - st] : 0;
    __syncthreads();
    lds[t] += v;
    __syncthreads();
  }
  if (t == 127) off[NN] = lds[127];
  if (t < NB1) psum[t] = t ? lds[t - 1] : 0;
}

// K3: blocks<NB1 run scan_c (node offsets); remaining blocks run bin_scatter.
__global__ void scanc_bin(const float* __restrict__ norm, const int* __restrict__ psum,
                          int* __restrict__ off,
                          const int* __restrict__ src, const int* __restrict__ dst,
                          const int* __restrict__ rid, int* __restrict__ bktcur,
                          unsigned* __restrict__ sval, unsigned short* __restrict__ sdst) {
  __shared__ int lds[256];
  __shared__ int hist[NBKT];
  __shared__ int base[NBKT];
  __shared__ int rnk[NBKT];
  int tid = threadIdx.x;
  if (blockIdx.x < NB1) {
    int b = blockIdx.x;
    int bb = b * 1024 + tid * 4;
    int v[4]; int s = 0;
#pragma unroll
    for (int j = 0; j < 4; j++) { int i = bb + j; v[j] = (i < NN) ? pdegf(norm[i]) : 0; s += v[j]; }
    lds[tid] = s; __syncthreads();
    for (int st = 1; st < 256; st <<= 1) {
      int u = (tid >= st) ? lds[tid - st] : 0;
      __syncthreads();
      lds[tid] += u;
      __syncthreads();
    }
    int run = (tid ? lds[tid - 1] : 0) + psum[b];
#pragma unroll
    for (int j = 0; j < 4; j++) {
      int i = bb + j;
      if (i < NN) { off[i] = run; run += v[j]; }
    }
  } else {
    int b = blockIdx.x - NB1;
    int e0 = b * EPB;
    for (int t = tid; t < NBKT; t += 256) hist[t] = 0;
    __syncthreads();
    int d[8];
#pragma unroll
    for (int j = 0; j < 8; j++) {
      int e = e0 + tid + j * 256;
      d[j] = (e < NE) ? dst[e] : -1;
      if (d[j] >= 0) atomicAdd(&hist[d[j] >> 9], 1);
    }
    __syncthreads();
    for (int t = tid; t < NBKT; t += 256) {
      base[t] = hist[t] ? atomicAdd(&bktcur[t], hist[t]) : 0;
      rnk[t] = 0;
    }
    __syncthreads();
#pragma unroll
    for (int j = 0; j < 8; j++) {
      if (d[j] >= 0) {
        int e = e0 + tid + j * 256;
        int bk = d[j] >> 9;
        int r = atomicAdd(&rnk[bk], 1);
        int pos = base[bk] + r;
        if (pos < CAP) {
          sval[(size_t)bk * CAP + pos] = (unsigned)src[e] | ((unsigned)rid[e] << 17);
          sdst[(size_t)bk * CAP + pos] = (unsigned short)(d[j] & 511);
        }
      }
    }
  }
}

// K4: one block per bucket; place staged edges at final epack slots, sentinel-pad.
__global__ void bin_sort(const int* __restrict__ bktcur, const unsigned* __restrict__ sval,
                         const unsigned short* __restrict__ sdst, const int* __restrict__ off,
                         unsigned* __restrict__ epack) {
  __shared__ int cur[512];
  int b = blockIdx.x, tid = threadIdx.x;
  int g0 = b << 9;
  for (int t = tid; t < 512; t += 256) {
    int g = g0 + t;
    cur[t] = (g < NN) ? off[g] : 0;
  }
  __syncthreads();
  int scnt = min(bktcur[b], CAP);
  for (int i = tid; i < scnt; i += 256) {
    unsigned v = sval[(size_t)b * CAP + i];
    int gl = sdst[(size_t)b * CAP + i];
    int pos = atomicAdd(&cur[gl], 1);
    epack[pos] = v;
  }
  __syncthreads();
  for (int t = tid; t < 512; t += 256) {
    int g = g0 + t;
    if (g < NN) {
      int s = cur[t], e = off[g + 1];
      for (; s < e; s++) epack[s] = SENT;
    }
  }
}

// layer-1 gather: 16 lanes/node, 16B loads, packed-f32 accum.
// Emits preb = bf16(nm*(Sh+Sr)) and relaggn = bf16(nm*Sr).
__global__ void gather1(const unsigned short* __restrict__ hb, const unsigned short* __restrict__ relb,
                        const float* __restrict__ norm, const int* __restrict__ off,
                        const unsigned* __restrict__ epack,
                        unsigned short* __restrict__ preb, unsigned short* __restrict__ relaggn) {
  int gid = blockIdx.x * blockDim.x + threadIdx.x;
  int g = gid >> 4;
  if (g >= NN) return;
  int cb = (gid & 15) << 3;  // 8 columns per lane
  int beg = off[g], end = off[g + 1];
  f32x2 ha[4], ra[4];
#pragma unroll
  for (int q = 0; q < 4; q++) { ha[q] = (f32x2){0.f, 0.f}; ra[q] = (f32x2){0.f, 0.f}; }
  for (int e = beg; e < end; e += 4) {
    u32x4 w = *(const u32x4*)(epack + e);
    u32x4 hv[4], rv[4];
#pragma unroll
    for (int j = 0; j < 4; j++) {
      int s = (int)(w[j] & 0x1FFFFu);
      int r = (int)(w[j] >> 17);
      hv[j] = *(const u32x4*)(hb + (size_t)s * DD + cb);
      rv[j] = *(const u32x4*)(relb + (size_t)r * DD + cb);
    }
#pragma unroll
    for (int j = 0; j < 4; j++) {
#pragma unroll
      for (int q = 0; q < 4; q++) {
        ha[q] += bf2f2(hv[j][q]);
        ra[q] += bf2f2(rv[j][q]);
      }
    }
  }
  float nm = norm[g];
  s16x8 p, qd;
#pragma unroll
  for (int q = 0; q < 4; q++) {
    p[2 * q]     = (short)f2b((ha[q][0] + ra[q][0]) * nm);
    p[2 * q + 1] = (short)f2b((ha[q][1] + ra[q][1]) * nm);
    qd[2 * q]     = (short)f2b(ra[q][0] * nm);
    qd[2 * q + 1] = (short)f2b(ra[q][1] * nm);
  }
  *(s16x8*)(preb + (size_t)g * DD + cb) = p;
  *(s16x8*)(relaggn + (size_t)g * DD + cb) = qd;
}

// layer-2 gather: h only, init from relaggn; same 16-lane structure.
__global__ void gather2(const unsigned short* __restrict__ hb, const unsigned short* __restrict__ relaggn,
                        const float* __restrict__ norm, const int* __restrict__ off,
                        const unsigned* __restrict__ epack, unsigned short* __restrict__ preb) {
  int gid = blockIdx.x * blockDim.x + threadIdx.x;
  int g = gid >> 4;
  if (g >= NN) return;
  int cb = (gid & 15) << 3;
  int beg = off[g], end = off[g + 1];
  f32x2 ha[4];
#pragma unroll
  for (int q = 0; q < 4; q++) ha[q] = (f32x2){0.f, 0.f};
  for (int e = beg; e < end; e += 4) {
    u32x4 w = *(const u32x4*)(epack + e);
    u32x4 hv[4];
#pragma unroll
    for (int j = 0; j < 4; j++) {
      int s = (int)(w[j] & 0x1FFFFu);
      hv[j] = *(const u32x4*)(hb + (size_t)s * DD + cb);
    }
#pragma unroll
    for (int j = 0; j < 4; j++) {
#pragma unroll
      for (int q = 0; q < 4; q++) ha[q] += bf2f2(hv[j][q]);
    }
  }
  float nm = norm[g];
  s16x8 raw = *(const s16x8*)(relaggn + (size_t)g * DD + cb);
  s16x8 p;
#pragma unroll
  for (int q = 0; q < 4; q++) {
    p[2 * q]     = (short)f2b(__builtin_fmaf(ha[q][0], nm, b2f(raw[2 * q])));
    p[2 * q + 1] = (short)f2b(__builtin_fmaf(ha[q][1], nm, b2f(raw[2 * q + 1])));
  }
  *(s16x8*)(preb + (size_t)g * DD + cb) = p;
}

// out = leaky_relu([preb ; hb] @ Wt). A-frags direct from global (bf16),
// fragment-major B in LDS (64KB, linear stage, conflict-free reads).
// Grid 512 = 2 blocks/CU; each wave owns tiles gw and gw+4096.
// OUTF32=0 writes bf16 in-place into hb (wave reads its 16 rows into regs
// before epilogue; rows partitioned across waves -> safe).
template <int OUTF32>
__launch_bounds__(512, 4)
__global__ void layer_mm(const unsigned short* __restrict__ preb, const unsigned short* __restrict__ hb,
                         const unsigned short* __restrict__ Wt, void* __restrict__ outp) {
  __shared__ unsigned short Blds[32768];
  int tid = threadIdx.x;
  int wave = tid >> 6, lane = tid & 63;
  int l16 = lane & 15, lhi = lane >> 4;

  for (int i = tid; i < 4096; i += 512)
    *(s16x8*)(&Blds[(size_t)i * 8]) = *(const s16x8*)(Wt + (size_t)i * 8);
  __syncthreads();

  const unsigned short* Bl = &Blds[lane * 8];

  int gw = blockIdx.x * 8 + wave;  // 0..4095
  int t0 = gw, t1 = gw + 4096;
  bool has1 = t1 < NTILE;

  const unsigned short* Ap0 = preb + (size_t)(t0 * 16 + l16) * DD + lhi * 8;
  const unsigned short* Ah0 = hb + (size_t)(t0 * 16 + l16) * DD + lhi * 8;
  s16x8 a0[8], a1[8];
#pragma unroll
  for (int ks = 0; ks < 4; ks++) a0[ks] = *(const s16x8*)(Ap0 + ks * 32);
#pragma unroll
  for (int ks = 0; ks < 4; ks++) a0[4 + ks] = *(const s16x8*)(Ah0 + ks * 32);
  if (has1) {
    const unsigned short* Ap1 = preb + (size_t)(t1 * 16 + l16) * DD + lhi * 8;
    const unsigned short* Ah1 = hb + (size_t)(t1 * 16 + l16) * DD + lhi * 8;
#pragma unroll
    for (int ks = 0; ks < 4; ks++) a1[ks] = *(const s16x8*)(Ap1 + ks * 32);
#pragma unroll
    for (int ks = 0; ks < 4; ks++) a1[4 + ks] = *(const s16x8*)(Ah1 + ks * 32);
  }

  {
    f32x4 acc[8];
#pragma unroll
    for (int n = 0; n < 8; n++) acc[n] = (f32x4){0.f, 0.f, 0.f, 0.f};
#pragma unroll
    for (int n = 0; n < 8; n++) {
#pragma unroll
      for (int k = 0; k < 8; k++) {
        s16x8 b = *(const s16x8*)(Bl + (n * 8 + k) * 512);
        acc[n] = __builtin_amdgcn_mfma_f32_16x16x32_bf16(a0[k], b, acc[n], 0, 0, 0);
      }
    }
    int r0 = t0 * 16;
#pragma unroll
    for (int n = 0; n < 8; n++) {
#pragma unroll
      for (int j = 0; j < 4; j++) {
        int gr = r0 + lhi * 4 + j;
        float x = acc[n][j];
        x = x > 0.f ? x : x * SLOPE;
        if (OUTF32) ((float*)outp)[(size_t)gr * DD + n * 16 + l16] = x;
        else ((unsigned short*)outp)[(size_t)gr * DD + n * 16 + l16] = f2b(x);
      }
    }
  }
  if (has1) {
    f32x4 acc[8];
#pragma unroll
    for (int n = 0; n < 8; n++) acc[n] = (f32x4){0.f, 0.f, 0.f, 0.f};
#pragma unroll
    for (int n = 0; n < 8; n++) {
#pragma unroll
      for (int k = 0; k < 8; k++) {
        s16x8 b = *(const s16x8*)(Bl + (n * 8 + k) * 512);
        acc[n] = __builtin_amdgcn_mfma_f32_16x16x32_bf16(a1[k], b, acc[n], 0, 0, 0);
      }
    }
    int r0 = t1 * 16;
#pragma unroll
    for (int n = 0; n < 8; n++) {
#pragma unroll
      for (int j = 0; j < 4; j++) {
        int gr = r0 + lhi * 4 + j;
        float x = acc[n][j];
        x = x > 0.f ? x : x * SLOPE;
        if (OUTF32) ((float*)outp)[(size_t)gr * DD + n * 16 + l16] = x;
        else ((unsigned short*)outp)[(size_t)gr * DD + n * 16 + l16] = f2b(x);
      }
    }
  }
}

extern "C" void kernel_launch(void* const* d_in, const int* in_sizes, int n_in,
                              void* d_out, int out_size, void* d_ws, size_t ws_size,
                              hipStream_t stream) {
  const float* ent  = (const float*)d_in[0];
  const float* rel  = (const float*)d_in[1];
  const float* norm = (const float*)d_in[2];
  const float* Wr0  = (const float*)d_in[3];
  const float* Wl0  = (const float*)d_in[4];
  const float* Wr1  = (const float*)d_in[5];
  const float* Wl1  = (const float*)d_in[6];
  const int* src = (const int*)d_in[7];
  const int* dst = (const int*)d_in[8];
  const int* rid = (const int*)d_in[9];
  float* out = (float*)d_out;

  char* ws = (char*)d_ws;
  unsigned short* entb    = (unsigned short*)ws;                  // (NN+1)*256 = 25,600,256 B
  unsigned short* preb    = (unsigned short*)(ws + 25600256);     // 25,600,000 B
  unsigned short* relagg  = (unsigned short*)(ws + 51200256);     // 25,600,000 B
  unsigned short* Wt      = (unsigned short*)(ws + 76800256);     //    131,072 B (fragment-major)
  unsigned short* relb    = (unsigned short*)(ws + 76931328);     // 501*256 = 128,256 B
  int* off    = (int*)(ws + 77059584);                            //    400,016 B
  int* bktcur = (int*)(ws + 77459600);                            //        784 B
  int* psum   = (int*)(ws + 77860384);                            //        512 B
  unsigned* epack = (unsigned*)(ws + 77860896);                   //  4,001,792 B
  // staging aliases relagg (dead until gather1):
  unsigned* sval = (unsigned*)relagg;                             //  9,633,792 B
  unsigned short* sdst = (unsigned short*)(ws + 51200256 + 9633792); // 4,816,896 B

  // K1: conversions + Wt + scan_a + bktcur zero
  prep_plus<<<((NN + 1) * 16 + 255) / 256, 256, 0, stream>>>(
      ent, rel, Wr0, Wl0, Wr1, Wl1, norm, entb, relb, Wt, psum, bktcur);
  // K2: scan of chunk sums
  scan_b<<<1, 128, 0, stream>>>(psum, off);
  // K3: node offsets || binned scatter to staging
  scanc_bin<<<NB1 + NBINB, 256, 0, stream>>>(norm, psum, off, src, dst, rid, bktcur, sval, sdst);
  // K4: bucket-local placement + sentinel pad
  bin_sort<<<NBKT, 256, 0, stream>>>(bktcur, sval, sdst, off, epack);

  const int gb = (NN * 16 + 255) / 256;  // 16 lanes per node

  // layer 1: gather ent+rel; mm writes bf16 h1 in place of entb
  gather1<<<gb, 256, 0, stream>>>(entb, relb, norm, off, epack, preb, relagg);
  layer_mm<0><<<512, 512, 0, stream>>>(preb, entb, Wt, entb);

  // layer 2: gather h1 (rel part cached in relagg); mm writes fp32 d_out
  gather2<<<gb, 256, 0, stream>>>(entb, relagg, norm, off, epack, preb);
  layer_mm<1><<<512, 512, 0, stream>>>(preb, entb, Wt + 32768, out);
}

// Round 12
// 145.077 us; speedup vs baseline: 1.1928x; 1.0158x over previous
//
#include <hip/hip_runtime.h>
#include <hip/hip_bf16.h>

#define NN 100000
#define NE 600000
#define DD 128
#define SLOPE 0.22916666666666666f
#define NB1 98  // ceil(NN/1024)
#define SENT ((500u << 17) | 100000u)  // decodes to zero rows hb[NN], relb[500]
#define NBKT 196                      // ceil(NN/512)
#define EPB 2048                      // edges per bin_scatter block
#define NBINB 293                     // ceil(NE/EPB)
#define CAP 12288                     // staging capacity per bucket
#define NTILE 6250                    // NN/16

typedef __attribute__((ext_vector_type(4))) float f32x4;
typedef __attribute__((ext_vector_type(2))) float f32x2;
typedef __attribute__((ext_vector_type(4))) unsigned u32x4;
typedef __attribute__((ext_vector_type(8))) short s16x8;
typedef __attribute__((ext_vector_type(4))) short s16x4;

__device__ __forceinline__ unsigned short f2b(float f) {
  union { float f; unsigned u; } v; v.f = f;
  unsigned u = v.u;
  return (unsigned short)((u + 0x7fffu + ((u >> 16) & 1u)) >> 16);
}
__device__ __forceinline__ float b2f(short s) {
  union { unsigned u; float f; } v;
  v.u = ((unsigned)(unsigned short)s) << 16;
  return v.f;
}
// unpack u32 (2 bf16) -> f32x2 {lo, hi}
__device__ __forceinline__ f32x2 bf2f2(unsigned u) {
  union { unsigned u; float f; } lo, hi;
  lo.u = u << 16; hi.u = u & 0xFFFF0000u;
  f32x2 r; r[0] = lo.f; r[1] = hi.f; return r;
}
// padded degree: 4*ceil(deg/4); deg from norm (deg0 nodes -> 4 sentinel slots)
__device__ __forceinline__ int pdegf(float nm) {
  int d = (int)(1.0f / nm + 0.5f);
  return (d + 3) & ~3;
}

// K1: ent->bf16 (+zero row NN), rel->bf16 (+zero row 500), Wt in MFMA-fragment
// order; blocks<NB1 also run scan_a (chunk sums); block NB1 zeroes bktcur.
__global__ void prep_plus(const float* __restrict__ ent, const float* __restrict__ rel,
                          const float* __restrict__ Wr0, const float* __restrict__ Wl0,
                          const float* __restrict__ Wr1, const float* __restrict__ Wl1,
                          const float* __restrict__ norm,
                          unsigned short* __restrict__ entb, unsigned short* __restrict__ relb,
                          unsigned short* __restrict__ Wt,
                          int* __restrict__ psum, int* __restrict__ bktcur) {
  __shared__ int lds[256];
  int i = blockIdx.x * blockDim.x + threadIdx.x;
  if (i < (NN + 1) * 16) {
    s16x8 o = {0, 0, 0, 0, 0, 0, 0, 0};
    if (i < NN * 16) {
      f32x4 v0 = *(const f32x4*)(ent + (size_t)i * 8);
      f32x4 v1 = *(const f32x4*)(ent + (size_t)i * 8 + 4);
      o[0] = (short)f2b(v0[0]); o[1] = (short)f2b(v0[1]);
      o[2] = (short)f2b(v0[2]); o[3] = (short)f2b(v0[3]);
      o[4] = (short)f2b(v1[0]); o[5] = (short)f2b(v1[1]);
      o[6] = (short)f2b(v1[2]); o[7] = (short)f2b(v1[3]);
    }
    *(s16x8*)(entb + (size_t)i * 8) = o;
  }
  if (i < 501 * 16) {
    s16x8 o = {0, 0, 0, 0, 0, 0, 0, 0};
    if (i < 500 * 16) {
      f32x4 v0 = *(const f32x4*)(rel + (size_t)i * 8);
      f32x4 v1 = *(const f32x4*)(rel + (size_t)i * 8 + 4);
      o[0] = (short)f2b(v0[0]); o[1] = (short)f2b(v0[1]);
      o[2] = (short)f2b(v0[2]); o[3] = (short)f2b(v0[3]);
      o[4] = (short)f2b(v1[0]); o[5] = (short)f2b(v1[1]);
      o[6] = (short)f2b(v1[2]); o[7] = (short)f2b(v1[3]);
    }
    *(s16x8*)(relb + (size_t)i * 8) = o;
  }
  if (i < 8192) {  // 2 layers x 4096 fragment units x 8 shorts
    int L = i >> 12, rem = i & 4095;
    int n = rem >> 9, k = (rem >> 6) & 7, lane = rem & 63;
    int c = n * 16 + (lane & 15);
    int kk0 = k * 32 + (lane >> 4) * 8;
    const float* Wr = L ? Wr1 : Wr0;
    const float* Wl = L ? Wl1 : Wl0;
    s16x8 o;
#pragma unroll
    for (int t = 0; t < 8; t++) {
      int kk = kk0 + t;
      float v = (kk < DD) ? Wr[kk * DD + c] : Wl[(kk - DD) * DD + c];
      o[t] = (short)f2b(v);
    }
    *(s16x8*)(Wt + (size_t)i * 8) = o;
  }
  if (blockIdx.x < NB1) {
    int b = blockIdx.x, t = threadIdx.x;
    int base = b * 1024 + t * 4;
    int s = 0;
#pragma unroll
    for (int j = 0; j < 4; j++) { int ii = base + j; if (ii < NN) s += pdegf(norm[ii]); }
    lds[t] = s; __syncthreads();
    for (int st = 128; st > 0; st >>= 1) { if (t < st) lds[t] += lds[t + st]; __syncthreads(); }
    if (t == 0) psum[b] = lds[0];
  } else if (blockIdx.x == NB1 && threadIdx.x < NBKT) {
    bktcur[threadIdx.x] = 0;
  }
}

// K2: blocks<NB1: node offsets (each block computes its own prefix over
// psum[0..b) -- scan_b launch eliminated; block NB1-1 writes off[NN]).
// Remaining blocks: binned scatter to per-bucket staging.
__global__ void scanc_bin(const float* __restrict__ norm, const int* __restrict__ psum,
                          int* __restrict__ off,
                          const int* __restrict__ src, const int* __restrict__ dst,
                          const int* __restrict__ rid, int* __restrict__ bktcur,
                          unsigned* __restrict__ sval, unsigned short* __restrict__ sdst) {
  __shared__ int lds[256];
  __shared__ int pfx[128];
  __shared__ int hist[NBKT];
  __shared__ int base[NBKT];
  __shared__ int rnk[NBKT];
  int tid = threadIdx.x;
  if (blockIdx.x < NB1) {
    int b = blockIdx.x;
    // prefix over psum[0..b)
    if (tid < 128) pfx[tid] = (tid < b) ? psum[tid] : 0;
    __syncthreads();
    if (tid < 64) { pfx[tid] += pfx[tid + 64]; }
    __syncthreads();
    if (tid < 32) { pfx[tid] += pfx[tid + 32]; }
    __syncthreads();
    if (tid < 16) { pfx[tid] += pfx[tid + 16]; }
    __syncthreads();
    if (tid < 8) { pfx[tid] += pfx[tid + 8]; }
    __syncthreads();
    if (tid < 4) { pfx[tid] += pfx[tid + 4]; }
    __syncthreads();
    if (tid < 2) { pfx[tid] += pfx[tid + 2]; }
    __syncthreads();
    if (tid == 0) pfx[0] += pfx[1];
    __syncthreads();
    int prefix = pfx[0];
    int bb = b * 1024 + tid * 4;
    int v[4]; int s = 0;
#pragma unroll
    for (int j = 0; j < 4; j++) { int i = bb + j; v[j] = (i < NN) ? pdegf(norm[i]) : 0; s += v[j]; }
    lds[tid] = s; __syncthreads();
    for (int st = 1; st < 256; st <<= 1) {
      int u = (tid >= st) ? lds[tid - st] : 0;
      __syncthreads();
      lds[tid] += u;
      __syncthreads();
    }
    int run = (tid ? lds[tid - 1] : 0) + prefix;
#pragma unroll
    for (int j = 0; j < 4; j++) {
      int i = bb + j;
      if (i < NN) { off[i] = run; run += v[j]; }
    }
    if (b == NB1 - 1 && tid == 255) off[NN] = run;  // grand total
  } else {
    int b = blockIdx.x - NB1;
    int e0 = b * EPB;
    for (int t = tid; t < NBKT; t += 256) hist[t] = 0;
    __syncthreads();
    int d[8];
#pragma unroll
    for (int j = 0; j < 8; j++) {
      int e = e0 + tid + j * 256;
      d[j] = (e < NE) ? dst[e] : -1;
      if (d[j] >= 0) atomicAdd(&hist[d[j] >> 9], 1);
    }
    __syncthreads();
    for (int t = tid; t < NBKT; t += 256) {
      base[t] = hist[t] ? atomicAdd(&bktcur[t], hist[t]) : 0;
      rnk[t] = 0;
    }
    __syncthreads();
#pragma unroll
    for (int j = 0; j < 8; j++) {
      if (d[j] >= 0) {
        int e = e0 + tid + j * 256;
        int bk = d[j] >> 9;
        int r = atomicAdd(&rnk[bk], 1);
        int pos = base[bk] + r;
        if (pos < CAP) {
          sval[(size_t)bk * CAP + pos] = (unsigned)src[e] | ((unsigned)rid[e] << 17);
          sdst[(size_t)bk * CAP + pos] = (unsigned short)(d[j] & 511);
        }
      }
    }
  }
}

// K3: one block per bucket; place staged edges at final epack slots, sentinel-pad.
__global__ void bin_sort(const int* __restrict__ bktcur, const unsigned* __restrict__ sval,
                         const unsigned short* __restrict__ sdst, const int* __restrict__ off,
                         unsigned* __restrict__ epack) {
  __shared__ int cur[512];
  int b = blockIdx.x, tid = threadIdx.x;
  int g0 = b << 9;
  for (int t = tid; t < 512; t += 256) {
    int g = g0 + t;
    cur[t] = (g < NN) ? off[g] : 0;
  }
  __syncthreads();
  int scnt = min(bktcur[b], CAP);
  for (int i = tid; i < scnt; i += 256) {
    unsigned v = sval[(size_t)b * CAP + i];
    int gl = sdst[(size_t)b * CAP + i];
    int pos = atomicAdd(&cur[gl], 1);
    epack[pos] = v;
  }
  __syncthreads();
  for (int t = tid; t < 512; t += 256) {
    int g = g0 + t;
    if (g < NN) {
      int s = cur[t], e = off[g + 1];
      for (; s < e; s++) epack[s] = SENT;
    }
  }
}

// layer-1 gather: 16 lanes/node, 16B loads, packed-f32 accum.
// Emits preb = bf16(nm*(Sh+Sr)) and relaggn = bf16(nm*Sr).
__global__ void gather1(const unsigned short* __restrict__ hb, const unsigned short* __restrict__ relb,
                        const float* __restrict__ norm, const int* __restrict__ off,
                        const unsigned* __restrict__ epack,
                        unsigned short* __restrict__ preb, unsigned short* __restrict__ relaggn) {
  int gid = blockIdx.x * blockDim.x + threadIdx.x;
  int g = gid >> 4;
  if (g >= NN) return;
  int cb = (gid & 15) << 3;  // 8 columns per lane
  int beg = off[g], end = off[g + 1];
  f32x2 ha[4], ra[4];
#pragma unroll
  for (int q = 0; q < 4; q++) { ha[q] = (f32x2){0.f, 0.f}; ra[q] = (f32x2){0.f, 0.f}; }
  for (int e = beg; e < end; e += 4) {
    u32x4 w = *(const u32x4*)(epack + e);
    u32x4 hv[4], rv[4];
#pragma unroll
    for (int j = 0; j < 4; j++) {
      int s = (int)(w[j] & 0x1FFFFu);
      int r = (int)(w[j] >> 17);
      hv[j] = *(const u32x4*)(hb + (size_t)s * DD + cb);
      rv[j] = *(const u32x4*)(relb + (size_t)r * DD + cb);
    }
#pragma unroll
    for (int j = 0; j < 4; j++) {
#pragma unroll
      for (int q = 0; q < 4; q++) {
        ha[q] += bf2f2(hv[j][q]);
        ra[q] += bf2f2(rv[j][q]);
      }
    }
  }
  float nm = norm[g];
  s16x8 p, qd;
#pragma unroll
  for (int q = 0; q < 4; q++) {
    p[2 * q]     = (short)f2b((ha[q][0] + ra[q][0]) * nm);
    p[2 * q + 1] = (short)f2b((ha[q][1] + ra[q][1]) * nm);
    qd[2 * q]     = (short)f2b(ra[q][0] * nm);
    qd[2 * q + 1] = (short)f2b(ra[q][1] * nm);
  }
  *(s16x8*)(preb + (size_t)g * DD + cb) = p;
  *(s16x8*)(relaggn + (size_t)g * DD + cb) = qd;
}

// layer-2 gather: h only, init from relaggn; same 16-lane structure.
__global__ void gather2(const unsigned short* __restrict__ hb, const unsigned short* __restrict__ relaggn,
                        const float* __restrict__ norm, const int* __restrict__ off,
                        const unsigned* __restrict__ epack, unsigned short* __restrict__ preb) {
  int gid = blockIdx.x * blockDim.x + threadIdx.x;
  int g = gid >> 4;
  if (g >= NN) return;
  int cb = (gid & 15) << 3;
  int beg = off[g], end = off[g + 1];
  f32x2 ha[4];
#pragma unroll
  for (int q = 0; q < 4; q++) ha[q] = (f32x2){0.f, 0.f};
  for (int e = beg; e < end; e += 4) {
    u32x4 w = *(const u32x4*)(epack + e);
    u32x4 hv[4];
#pragma unroll
    for (int j = 0; j < 4; j++) {
      int s = (int)(w[j] & 0x1FFFFu);
      hv[j] = *(const u32x4*)(hb + (size_t)s * DD + cb);
    }
#pragma unroll
    for (int j = 0; j < 4; j++) {
#pragma unroll
      for (int q = 0; q < 4; q++) ha[q] += bf2f2(hv[j][q]);
    }
  }
  float nm = norm[g];
  s16x8 raw = *(const s16x8*)(relaggn + (size_t)g * DD + cb);
  s16x8 p;
#pragma unroll
  for (int q = 0; q < 4; q++) {
    p[2 * q]     = (short)f2b(__builtin_fmaf(ha[q][0], nm, b2f(raw[2 * q])));
    p[2 * q + 1] = (short)f2b(__builtin_fmaf(ha[q][1], nm, b2f(raw[2 * q + 1])));
  }
  *(s16x8*)(preb + (size_t)g * DD + cb) = p;
}

// out = leaky_relu([preb ; hb] @ Wt). A-frag loads issued FIRST (critical
// path), then B staged to LDS (fragment-major, conflict-free). Grid 512 =
// 2 blocks/CU; each wave owns tiles gw and gw+4096.
// OUTF32=0 writes bf16 in-place into hb (rows partitioned across waves).
template <int OUTF32>
__launch_bounds__(512, 4)
__global__ void layer_mm(const unsigned short* __restrict__ preb, const unsigned short* __restrict__ hb,
                         const unsigned short* __restrict__ Wt, void* __restrict__ outp) {
  __shared__ unsigned short Blds[32768];
  int tid = threadIdx.x;
  int wave = tid >> 6, lane = tid & 63;
  int l16 = lane & 15, lhi = lane >> 4;

  int gw = blockIdx.x * 8 + wave;  // 0..4095
  int t0 = gw, t1 = gw + 4096;
  bool has1 = t1 < NTILE;

  // issue A loads first -- their latency overlaps B staging + barrier
  const unsigned short* Ap0 = preb + (size_t)(t0 * 16 + l16) * DD + lhi * 8;
  const unsigned short* Ah0 = hb + (size_t)(t0 * 16 + l16) * DD + lhi * 8;
  s16x8 a0[8], a1[8];
#pragma unroll
  for (int ks = 0; ks < 4; ks++) a0[ks] = *(const s16x8*)(Ap0 + ks * 32);
#pragma unroll
  for (int ks = 0; ks < 4; ks++) a0[4 + ks] = *(const s16x8*)(Ah0 + ks * 32);
  if (has1) {
    const unsigned short* Ap1 = preb + (size_t)(t1 * 16 + l16) * DD + lhi * 8;
    const unsigned short* Ah1 = hb + (size_t)(t1 * 16 + l16) * DD + lhi * 8;
#pragma unroll
    for (int ks = 0; ks < 4; ks++) a1[ks] = *(const s16x8*)(Ap1 + ks * 32);
#pragma unroll
    for (int ks = 0; ks < 4; ks++) a1[4 + ks] = *(const s16x8*)(Ah1 + ks * 32);
  }

  for (int i = tid; i < 4096; i += 512)
    *(s16x8*)(&Blds[(size_t)i * 8]) = *(const s16x8*)(Wt + (size_t)i * 8);
  __syncthreads();

  const unsigned short* Bl = &Blds[lane * 8];

  {
    f32x4 acc[8];
#pragma unroll
    for (int n = 0; n < 8; n++) acc[n] = (f32x4){0.f, 0.f, 0.f, 0.f};
#pragma unroll
    for (int n = 0; n < 8; n++) {
#pragma unroll
      for (int k = 0; k < 8; k++) {
        s16x8 b = *(const s16x8*)(Bl + (n * 8 + k) * 512);
        acc[n] = __builtin_amdgcn_mfma_f32_16x16x32_bf16(a0[k], b, acc[n], 0, 0, 0);
      }
    }
    int r0 = t0 * 16;
#pragma unroll
    for (int n = 0; n < 8; n++) {
#pragma unroll
      for (int j = 0; j < 4; j++) {
        int gr = r0 + lhi * 4 + j;
        float x = acc[n][j];
        x = x > 0.f ? x : x * SLOPE;
        if (OUTF32) ((float*)outp)[(size_t)gr * DD + n * 16 + l16] = x;
        else ((unsigned short*)outp)[(size_t)gr * DD + n * 16 + l16] = f2b(x);
      }
    }
  }
  if (has1) {
    f32x4 acc[8];
#pragma unroll
    for (int n = 0; n < 8; n++) acc[n] = (f32x4){0.f, 0.f, 0.f, 0.f};
#pragma unroll
    for (int n = 0; n < 8; n++) {
#pragma unroll
      for (int k = 0; k < 8; k++) {
        s16x8 b = *(const s16x8*)(Bl + (n * 8 + k) * 512);
        acc[n] = __builtin_amdgcn_mfma_f32_16x16x32_bf16(a1[k], b, acc[n], 0, 0, 0);
      }
    }
    int r0 = t1 * 16;
#pragma unroll
    for (int n = 0; n < 8; n++) {
#pragma unroll
      for (int j = 0; j < 4; j++) {
        int gr = r0 + lhi * 4 + j;
        float x = acc[n][j];
        x = x > 0.f ? x : x * SLOPE;
        if (OUTF32) ((float*)outp)[(size_t)gr * DD + n * 16 + l16] = x;
        else ((unsigned short*)outp)[(size_t)gr * DD + n * 16 + l16] = f2b(x);
      }
    }
  }
}

extern "C" void kernel_launch(void* const* d_in, const int* in_sizes, int n_in,
                              void* d_out, int out_size, void* d_ws, size_t ws_size,
                              hipStream_t stream) {
  const float* ent  = (const float*)d_in[0];
  const float* rel  = (const float*)d_in[1];
  const float* norm = (const float*)d_in[2];
  const float* Wr0  = (const float*)d_in[3];
  const float* Wl0  = (const float*)d_in[4];
  const float* Wr1  = (const float*)d_in[5];
  const float* Wl1  = (const float*)d_in[6];
  const int* src = (const int*)d_in[7];
  const int* dst = (const int*)d_in[8];
  const int* rid = (const int*)d_in[9];
  float* out = (float*)d_out;

  char* ws = (char*)d_ws;
  unsigned short* entb    = (unsigned short*)ws;                  // (NN+1)*256 = 25,600,256 B
  unsigned short* preb    = (unsigned short*)(ws + 25600256);     // 25,600,000 B
  unsigned short* relagg  = (unsigned short*)(ws + 51200256);     // 25,600,000 B
  unsigned short* Wt      = (unsigned short*)(ws + 76800256);     //    131,072 B (fragment-major)
  unsigned short* relb    = (unsigned short*)(ws + 76931328);     // 501*256 = 128,256 B
  int* off    = (int*)(ws + 77059584);                            //    400,016 B
  int* bktcur = (int*)(ws + 77459600);                            //        784 B
  int* psum   = (int*)(ws + 77860384);                            //        512 B
  unsigned* epack = (unsigned*)(ws + 77860896);                   //  4,001,792 B
  // staging aliases relagg (dead until gather1):
  unsigned* sval = (unsigned*)relagg;                             //  9,633,792 B
  unsigned short* sdst = (unsigned short*)(ws + 51200256 + 9633792); // 4,816,896 B

  // K1: conversions + Wt + chunk degree sums + bktcur zero
  prep_plus<<<((NN + 1) * 16 + 255) / 256, 256, 0, stream>>>(
      ent, rel, Wr0, Wl0, Wr1, Wl1, norm, entb, relb, Wt, psum, bktcur);
  // K2: node offsets (self-prefixed) || binned scatter to staging
  scanc_bin<<<NB1 + NBINB, 256, 0, stream>>>(norm, psum, off, src, dst, rid, bktcur, sval, sdst);
  // K3: bucket-local placement + sentinel pad
  bin_sort<<<NBKT, 256, 0, stream>>>(bktcur, sval, sdst, off, epack);

  const int gb = (NN * 16 + 255) / 256;  // 16 lanes per node

  // layer 1: gather ent+rel; mm writes bf16 h1 in place of entb
  gather1<<<gb, 256, 0, stream>>>(entb, relb, norm, off, epack, preb, relagg);
  layer_mm<0><<<512, 512, 0, stream>>>(preb, entb, Wt, entb);

  // layer 2: gather h1 (rel part cached in relagg); mm writes fp32 d_out
  gather2<<<gb, 256, 0, stream>>>(entb, relagg, norm, off, epack, preb);
  layer_mm<1><<<512, 512, 0, stream>>>(preb, entb, Wt + 32768, out);
}

// Round 13
// 139.371 us; speedup vs baseline: 1.2416x; 1.0409x over previous
//
#include <hip/hip_runtime.h>
#include <hip/hip_bf16.h>

#define NN 100000
#define NE 600000
#define DD 128
#define SLOPE 0.22916666666666666f
#define NB1 98  // ceil(NN/1024)
#define SENT ((500u << 17) | 100000u)  // decodes to zero rows hb[NN], relb[500]
#define NBKT 196                      // ceil(NN/512)
#define EPB 2048                      // edges per bin_scatter block
#define NBINB 293                     // ceil(NE/EPB)
#define CAP 12288                     // staging capacity per bucket
#define NTILE 6250                    // NN/16

typedef __attribute__((ext_vector_type(4))) float f32x4;
typedef __attribute__((ext_vector_type(2))) float f32x2;
typedef __attribute__((ext_vector_type(4))) unsigned u32x4;
typedef __attribute__((ext_vector_type(8))) short s16x8;
typedef __attribute__((ext_vector_type(4))) short s16x4;

__device__ __forceinline__ unsigned short f2b(float f) {
  union { float f; unsigned u; } v; v.f = f;
  unsigned u = v.u;
  return (unsigned short)((u + 0x7fffu + ((u >> 16) & 1u)) >> 16);
}
__device__ __forceinline__ float b2f(short s) {
  union { unsigned u; float f; } v;
  v.u = ((unsigned)(unsigned short)s) << 16;
  return v.f;
}
// unpack u32 (2 bf16) -> f32x2 {lo, hi}
__device__ __forceinline__ f32x2 bf2f2(unsigned u) {
  union { unsigned u; float f; } lo, hi;
  lo.u = u << 16; hi.u = u & 0xFFFF0000u;
  f32x2 r; r[0] = lo.f; r[1] = hi.f; return r;
}
// padded degree: 4*ceil(deg/4); deg from norm (deg0 nodes -> 4 sentinel slots)
__device__ __forceinline__ int pdegf(float nm) {
  int d = (int)(1.0f / nm + 0.5f);
  return (d + 3) & ~3;
}

// K1: ent->bf16 (+zero row NN), rel->bf16 (+zero row 500), Wt in MFMA-fragment
// order; blocks<NB1 also run scan_a (chunk sums); block NB1 zeroes bktcur.
__global__ void prep_plus(const float* __restrict__ ent, const float* __restrict__ rel,
                          const float* __restrict__ Wr0, const float* __restrict__ Wl0,
                          const float* __restrict__ Wr1, const float* __restrict__ Wl1,
                          const float* __restrict__ norm,
                          unsigned short* __restrict__ entb, unsigned short* __restrict__ relb,
                          unsigned short* __restrict__ Wt,
                          int* __restrict__ psum, int* __restrict__ bktcur) {
  __shared__ int lds[256];
  int i = blockIdx.x * blockDim.x + threadIdx.x;
  if (i < (NN + 1) * 16) {
    s16x8 o = {0, 0, 0, 0, 0, 0, 0, 0};
    if (i < NN * 16) {
      f32x4 v0 = *(const f32x4*)(ent + (size_t)i * 8);
      f32x4 v1 = *(const f32x4*)(ent + (size_t)i * 8 + 4);
      o[0] = (short)f2b(v0[0]); o[1] = (short)f2b(v0[1]);
      o[2] = (short)f2b(v0[2]); o[3] = (short)f2b(v0[3]);
      o[4] = (short)f2b(v1[0]); o[5] = (short)f2b(v1[1]);
      o[6] = (short)f2b(v1[2]); o[7] = (short)f2b(v1[3]);
    }
    *(s16x8*)(entb + (size_t)i * 8) = o;
  }
  if (i < 501 * 16) {
    s16x8 o = {0, 0, 0, 0, 0, 0, 0, 0};
    if (i < 500 * 16) {
      f32x4 v0 = *(const f32x4*)(rel + (size_t)i * 8);
      f32x4 v1 = *(const f32x4*)(rel + (size_t)i * 8 + 4);
      o[0] = (short)f2b(v0[0]); o[1] = (short)f2b(v0[1]);
      o[2] = (short)f2b(v0[2]); o[3] = (short)f2b(v0[3]);
      o[4] = (short)f2b(v1[0]); o[5] = (short)f2b(v1[1]);
      o[6] = (short)f2b(v1[2]); o[7] = (short)f2b(v1[3]);
    }
    *(s16x8*)(relb + (size_t)i * 8) = o;
  }
  if (i < 8192) {  // 2 layers x 4096 fragment units x 8 shorts
    int L = i >> 12, rem = i & 4095;
    int n = rem >> 9, k = (rem >> 6) & 7, lane = rem & 63;
    int c = n * 16 + (lane & 15);
    int kk0 = k * 32 + (lane >> 4) * 8;
    const float* Wr = L ? Wr1 : Wr0;
    const float* Wl = L ? Wl1 : Wl0;
    s16x8 o;
#pragma unroll
    for (int t = 0; t < 8; t++) {
      int kk = kk0 + t;
      float v = (kk < DD) ? Wr[kk * DD + c] : Wl[(kk - DD) * DD + c];
      o[t] = (short)f2b(v);
    }
    *(s16x8*)(Wt + (size_t)i * 8) = o;
  }
  if (blockIdx.x < NB1) {
    int b = blockIdx.x, t = threadIdx.x;
    int base = b * 1024 + t * 4;
    int s = 0;
#pragma unroll
    for (int j = 0; j < 4; j++) { int ii = base + j; if (ii < NN) s += pdegf(norm[ii]); }
    lds[t] = s; __syncthreads();
    for (int st = 128; st > 0; st >>= 1) { if (t < st) lds[t] += lds[t + st]; __syncthreads(); }
    if (t == 0) psum[b] = lds[0];
  } else if (blockIdx.x == NB1 && threadIdx.x < NBKT) {
    bktcur[threadIdx.x] = 0;
  }
}

// K2: blocks<NB1: node offsets (self-prefixed over psum; last block writes
// off[NN]). Remaining blocks: binned scatter to per-bucket staging.
__global__ void scanc_bin(const float* __restrict__ norm, const int* __restrict__ psum,
                          int* __restrict__ off,
                          const int* __restrict__ src, const int* __restrict__ dst,
                          const int* __restrict__ rid, int* __restrict__ bktcur,
                          unsigned* __restrict__ sval, unsigned short* __restrict__ sdst) {
  __shared__ int lds[256];
  __shared__ int pfx[128];
  __shared__ int hist[NBKT];
  __shared__ int base[NBKT];
  __shared__ int rnk[NBKT];
  int tid = threadIdx.x;
  if (blockIdx.x < NB1) {
    int b = blockIdx.x;
    if (tid < 128) pfx[tid] = (tid < b) ? psum[tid] : 0;
    __syncthreads();
    if (tid < 64) { pfx[tid] += pfx[tid + 64]; }
    __syncthreads();
    if (tid < 32) { pfx[tid] += pfx[tid + 32]; }
    __syncthreads();
    if (tid < 16) { pfx[tid] += pfx[tid + 16]; }
    __syncthreads();
    if (tid < 8) { pfx[tid] += pfx[tid + 8]; }
    __syncthreads();
    if (tid < 4) { pfx[tid] += pfx[tid + 4]; }
    __syncthreads();
    if (tid < 2) { pfx[tid] += pfx[tid + 2]; }
    __syncthreads();
    if (tid == 0) pfx[0] += pfx[1];
    __syncthreads();
    int prefix = pfx[0];
    int bb = b * 1024 + tid * 4;
    int v[4]; int s = 0;
#pragma unroll
    for (int j = 0; j < 4; j++) { int i = bb + j; v[j] = (i < NN) ? pdegf(norm[i]) : 0; s += v[j]; }
    lds[tid] = s; __syncthreads();
    for (int st = 1; st < 256; st <<= 1) {
      int u = (tid >= st) ? lds[tid - st] : 0;
      __syncthreads();
      lds[tid] += u;
      __syncthreads();
    }
    int run = (tid ? lds[tid - 1] : 0) + prefix;
#pragma unroll
    for (int j = 0; j < 4; j++) {
      int i = bb + j;
      if (i < NN) { off[i] = run; run += v[j]; }
    }
    if (b == NB1 - 1 && tid == 255) off[NN] = run;
  } else {
    int b = blockIdx.x - NB1;
    int e0 = b * EPB;
    for (int t = tid; t < NBKT; t += 256) hist[t] = 0;
    __syncthreads();
    int d[8];
#pragma unroll
    for (int j = 0; j < 8; j++) {
      int e = e0 + tid + j * 256;
      d[j] = (e < NE) ? dst[e] : -1;
      if (d[j] >= 0) atomicAdd(&hist[d[j] >> 9], 1);
    }
    __syncthreads();
    for (int t = tid; t < NBKT; t += 256) {
      base[t] = hist[t] ? atomicAdd(&bktcur[t], hist[t]) : 0;
      rnk[t] = 0;
    }
    __syncthreads();
#pragma unroll
    for (int j = 0; j < 8; j++) {
      if (d[j] >= 0) {
        int e = e0 + tid + j * 256;
        int bk = d[j] >> 9;
        int r = atomicAdd(&rnk[bk], 1);
        int pos = base[bk] + r;
        if (pos < CAP) {
          sval[(size_t)bk * CAP + pos] = (unsigned)src[e] | ((unsigned)rid[e] << 17);
          sdst[(size_t)bk * CAP + pos] = (unsigned short)(d[j] & 511);
        }
      }
    }
  }
}

// K3: one block per bucket; place staged edges at final epack slots, sentinel-pad.
__global__ void bin_sort(const int* __restrict__ bktcur, const unsigned* __restrict__ sval,
                         const unsigned short* __restrict__ sdst, const int* __restrict__ off,
                         unsigned* __restrict__ epack) {
  __shared__ int cur[512];
  int b = blockIdx.x, tid = threadIdx.x;
  int g0 = b << 9;
  for (int t = tid; t < 512; t += 256) {
    int g = g0 + t;
    cur[t] = (g < NN) ? off[g] : 0;
  }
  __syncthreads();
  int scnt = min(bktcur[b], CAP);
  for (int i = tid; i < scnt; i += 256) {
    unsigned v = sval[(size_t)b * CAP + i];
    int gl = sdst[(size_t)b * CAP + i];
    int pos = atomicAdd(&cur[gl], 1);
    epack[pos] = v;
  }
  __syncthreads();
  for (int t = tid; t < 512; t += 256) {
    int g = g0 + t;
    if (g < NN) {
      int s = cur[t], e = off[g + 1];
      for (; s < e; s++) epack[s] = SENT;
    }
  }
}

// gather (both layers): 16 lanes/node, 16B loads, packed-f32 accum of h + rel;
// preb = bf16(nm*(Sh+Sr)). rel table is 128KB (L2-resident) -> rel loads are
// cheap; no relagg cache round-trip.
__global__ void gather(const unsigned short* __restrict__ hb, const unsigned short* __restrict__ relb,
                       const float* __restrict__ norm, const int* __restrict__ off,
                       const unsigned* __restrict__ epack, unsigned short* __restrict__ preb) {
  int gid = blockIdx.x * blockDim.x + threadIdx.x;
  int g = gid >> 4;
  if (g >= NN) return;
  int cb = (gid & 15) << 3;  // 8 columns per lane
  int beg = off[g], end = off[g + 1];
  f32x2 ha[4], ra[4];
#pragma unroll
  for (int q = 0; q < 4; q++) { ha[q] = (f32x2){0.f, 0.f}; ra[q] = (f32x2){0.f, 0.f}; }
  for (int e = beg; e < end; e += 4) {
    u32x4 w = *(const u32x4*)(epack + e);
    u32x4 hv[4], rv[4];
#pragma unroll
    for (int j = 0; j < 4; j++) {
      int s = (int)(w[j] & 0x1FFFFu);
      int r = (int)(w[j] >> 17);
      hv[j] = *(const u32x4*)(hb + (size_t)s * DD + cb);
      rv[j] = *(const u32x4*)(relb + (size_t)r * DD + cb);
    }
#pragma unroll
    for (int j = 0; j < 4; j++) {
#pragma unroll
      for (int q = 0; q < 4; q++) {
        ha[q] += bf2f2(hv[j][q]);
        ra[q] += bf2f2(rv[j][q]);
      }
    }
  }
  float nm = norm[g];
  s16x8 p;
#pragma unroll
  for (int q = 0; q < 4; q++) {
    p[2 * q]     = (short)f2b((ha[q][0] + ra[q][0]) * nm);
    p[2 * q + 1] = (short)f2b((ha[q][1] + ra[q][1]) * nm);
  }
  *(s16x8*)(preb + (size_t)g * DD + cb) = p;
}

// out = leaky_relu([preb ; hb] @ Wt). A-frag loads issued FIRST (critical
// path), then B staged to LDS (fragment-major, conflict-free). Grid 512 =
// 2 blocks/CU; each wave owns tiles gw and gw+4096.
// OUTF32=0 writes bf16 in-place into hb (rows partitioned across waves).
template <int OUTF32>
__launch_bounds__(512, 4)
__global__ void layer_mm(const unsigned short* __restrict__ preb, const unsigned short* __restrict__ hb,
                         const unsigned short* __restrict__ Wt, void* __restrict__ outp) {
  __shared__ unsigned short Blds[32768];
  int tid = threadIdx.x;
  int wave = tid >> 6, lane = tid & 63;
  int l16 = lane & 15, lhi = lane >> 4;

  int gw = blockIdx.x * 8 + wave;  // 0..4095
  int t0 = gw, t1 = gw + 4096;
  bool has1 = t1 < NTILE;

  const unsigned short* Ap0 = preb + (size_t)(t0 * 16 + l16) * DD + lhi * 8;
  const unsigned short* Ah0 = hb + (size_t)(t0 * 16 + l16) * DD + lhi * 8;
  s16x8 a0[8], a1[8];
#pragma unroll
  for (int ks = 0; ks < 4; ks++) a0[ks] = *(const s16x8*)(Ap0 + ks * 32);
#pragma unroll
  for (int ks = 0; ks < 4; ks++) a0[4 + ks] = *(const s16x8*)(Ah0 + ks * 32);
  if (has1) {
    const unsigned short* Ap1 = preb + (size_t)(t1 * 16 + l16) * DD + lhi * 8;
    const unsigned short* Ah1 = hb + (size_t)(t1 * 16 + l16) * DD + lhi * 8;
#pragma unroll
    for (int ks = 0; ks < 4; ks++) a1[ks] = *(const s16x8*)(Ap1 + ks * 32);
#pragma unroll
    for (int ks = 0; ks < 4; ks++) a1[4 + ks] = *(const s16x8*)(Ah1 + ks * 32);
  }

  for (int i = tid; i < 4096; i += 512)
    *(s16x8*)(&Blds[(size_t)i * 8]) = *(const s16x8*)(Wt + (size_t)i * 8);
  __syncthreads();

  const unsigned short* Bl = &Blds[lane * 8];

  {
    f32x4 acc[8];
#pragma unroll
    for (int n = 0; n < 8; n++) acc[n] = (f32x4){0.f, 0.f, 0.f, 0.f};
#pragma unroll
    for (int n = 0; n < 8; n++) {
#pragma unroll
      for (int k = 0; k < 8; k++) {
        s16x8 b = *(const s16x8*)(Bl + (n * 8 + k) * 512);
        acc[n] = __builtin_amdgcn_mfma_f32_16x16x32_bf16(a0[k], b, acc[n], 0, 0, 0);
      }
    }
    int r0 = t0 * 16;
#pragma unroll
    for (int n = 0; n < 8; n++) {
#pragma unroll
      for (int j = 0; j < 4; j++) {
        int gr = r0 + lhi * 4 + j;
        float x = acc[n][j];
        x = x > 0.f ? x : x * SLOPE;
        if (OUTF32) ((float*)outp)[(size_t)gr * DD + n * 16 + l16] = x;
        else ((unsigned short*)outp)[(size_t)gr * DD + n * 16 + l16] = f2b(x);
      }
    }
  }
  if (has1) {
    f32x4 acc[8];
#pragma unroll
    for (int n = 0; n < 8; n++) acc[n] = (f32x4){0.f, 0.f, 0.f, 0.f};
#pragma unroll
    for (int n = 0; n < 8; n++) {
#pragma unroll
      for (int k = 0; k < 8; k++) {
        s16x8 b = *(const s16x8*)(Bl + (n * 8 + k) * 512);
        acc[n] = __builtin_amdgcn_mfma_f32_16x16x32_bf16(a1[k], b, acc[n], 0, 0, 0);
      }
    }
    int r0 = t1 * 16;
#pragma unroll
    for (int n = 0; n < 8; n++) {
#pragma unroll
      for (int j = 0; j < 4; j++) {
        int gr = r0 + lhi * 4 + j;
        float x = acc[n][j];
        x = x > 0.f ? x : x * SLOPE;
        if (OUTF32) ((float*)outp)[(size_t)gr * DD + n * 16 + l16] = x;
        else ((unsigned short*)outp)[(size_t)gr * DD + n * 16 + l16] = f2b(x);
      }
    }
  }
}

extern "C" void kernel_launch(void* const* d_in, const int* in_sizes, int n_in,
                              void* d_out, int out_size, void* d_ws, size_t ws_size,
                              hipStream_t stream) {
  const float* ent  = (const float*)d_in[0];
  const float* rel  = (const float*)d_in[1];
  const float* norm = (const float*)d_in[2];
  const float* Wr0  = (const float*)d_in[3];
  const float* Wl0  = (const float*)d_in[4];
  const float* Wr1  = (const float*)d_in[5];
  const float* Wl1  = (const float*)d_in[6];
  const int* src = (const int*)d_in[7];
  const int* dst = (const int*)d_in[8];
  const int* rid = (const int*)d_in[9];
  float* out = (float*)d_out;

  char* ws = (char*)d_ws;
  unsigned short* entb = (unsigned short*)ws;                  // (NN+1)*256 = 25,600,256 B
  unsigned short* preb = (unsigned short*)(ws + 25600256);     // 25,600,000 B
  unsigned short* Wt   = (unsigned short*)(ws + 51200256);     //    131,072 B (fragment-major)
  unsigned short* relb = (unsigned short*)(ws + 51331328);     // 501*256 = 128,256 B
  int* off    = (int*)(ws + 51459584);                         //    400,016 B
  int* bktcur = (int*)(ws + 51859600);                         //        784 B
  int* psum   = (int*)(ws + 51860384);                         //        512 B
  unsigned* epack = (unsigned*)(ws + 51860896);                //  4,001,792 B
  // staging aliases preb (dead until first gather):
  unsigned* sval = (unsigned*)preb;                            //  9,633,792 B
  unsigned short* sdst = (unsigned short*)(ws + 25600256 + 9633792); // 4,816,896 B

  // K1: conversions + Wt + chunk degree sums + bktcur zero
  prep_plus<<<((NN + 1) * 16 + 255) / 256, 256, 0, stream>>>(
      ent, rel, Wr0, Wl0, Wr1, Wl1, norm, entb, relb, Wt, psum, bktcur);
  // K2: node offsets (self-prefixed) || binned scatter to staging
  scanc_bin<<<NB1 + NBINB, 256, 0, stream>>>(norm, psum, off, src, dst, rid, bktcur, sval, sdst);
  // K3: bucket-local placement + sentinel pad
  bin_sort<<<NBKT, 256, 0, stream>>>(bktcur, sval, sdst, off, epack);

  const int gb = (NN * 16 + 255) / 256;  // 16 lanes per node

  // layer 1: gather ent+rel; mm writes bf16 h1 in place of entb
  gather<<<gb, 256, 0, stream>>>(entb, relb, norm, off, epack, preb);
  layer_mm<0><<<512, 512, 0, stream>>>(preb, entb, Wt, entb);

  // layer 2: gather h1+rel; mm writes fp32 d_out
  gather<<<gb, 256, 0, stream>>>(entb, relb, norm, off, epack, preb);
  layer_mm<1><<<512, 512, 0, stream>>>(preb, entb, Wt + 32768, out);
}